// Round 9
// baseline (1066.844 us; speedup 1.0000x reference)
//
#include <hip/hip_runtime.h>

// EncoderLayer: B=8, D=512, S=4096, F=2048. fp32 in / fp32 out (proven R4).
// R8 @1021us: flash_attn = 507us, MfmaUtil 23%, FETCH 278MB (ideal ~70) —
// latency-bound: batch spread over all XCDs (64MB working set vs 4MB L2) and
// PV's Vt global loads exposed. R9: (1) batch = linear_id % G role remap so
// each XCD serves one batch (L2-hot K/Vt, cheap barrier drains); (2) Vt
// fragments register-prefetched at kt-loop top, latency hidden under S1.

typedef unsigned short u16;
typedef __attribute__((ext_vector_type(4))) float f32x4;
typedef __attribute__((ext_vector_type(8))) short s16x8;

__device__ __forceinline__ float bf2f(u16 u) {
    unsigned int v = ((unsigned int)u) << 16;
    float f;
    __builtin_memcpy(&f, &v, 4);
    return f;
}
__device__ __forceinline__ u16 f2bf(float f) {
    unsigned int v;
    __builtin_memcpy(&v, &f, 4);
    unsigned int r = (v + 0x7fffu + ((v >> 16) & 1u)) >> 16;
    return (u16)r;
}
__device__ __forceinline__ u16 loadbf(const void* p, long long i, int f32) {
    return f32 ? f2bf(((const float*)p)[i]) : ((const u16*)p)[i];
}

#if defined(__has_builtin)
#if __has_builtin(__builtin_amdgcn_global_load_lds)
#define HAS_GLDS 1
#endif
#endif
#ifndef HAS_GLDS
#define HAS_GLDS 0
#endif

#if HAS_GLDS
__device__ __forceinline__ void glds16(const u16* g, u16* l) {
    __builtin_amdgcn_global_load_lds(
        (const __attribute__((address_space(1))) void*)g,
        (__attribute__((address_space(3))) void*)l, 16, 0, 0);
}
#else
__device__ __forceinline__ void glds16(const u16* g, u16* l) {
    *(int4*)l = *(const int4*)g;
}
#endif

// ---------------------------------------------------------------------------
// Input dtype detection (fp32 vs bf16) for all 9 inputs in ONE dispatch.
// ---------------------------------------------------------------------------
struct DetectArgs { const u16* p[9]; int n[9]; };

__global__ __launch_bounds__(256) void detect9(DetectArgs a, int* __restrict__ flags)
{
    const u16* p = a.p[blockIdx.x];
    const int n_u16 = a.n[blockIdx.x];
    int insane = 0;
    for (int i = threadIdx.x; i < n_u16; i += 256) {
        u16 h = p[i];
        int e = (h >> 7) & 0xFF;
        int m = h & 0x7F;
        bool sane = (e >= 96 && e <= 141) || (e == 0 && m == 0);
        insane += sane ? 0 : 1;
    }
#pragma unroll
    for (int off = 32; off > 0; off >>= 1) insane += __shfl_down(insane, off);
    __shared__ int red[4];
    if ((threadIdx.x & 63) == 0) red[threadIdx.x >> 6] = insane;
    __syncthreads();
    if (threadIdx.x == 0)
        flags[blockIdx.x] = (red[0] + red[1] + red[2] + red[3] > n_u16 / 4) ? 1 : 0;
}

// ---------------------------------------------------------------------------
// bf16 MFMA GEMM (R7 structure: dbuf glds + XOR k-chunk swizzle + XCD swizzle)
// ---------------------------------------------------------------------------
#define BM 128
#define BN 128
#define BK 32

template <typename OutT, bool BIAS, bool RELU>
__global__ __launch_bounds__(256) void gemm_bt(
    const u16* __restrict__ A, const u16* __restrict__ Bt, OutT* __restrict__ C,
    const u16* __restrict__ bias, int M, int N, int K,
    int lda, int ldb, int ldc, int wmod,
    long long aZ, long long aW, long long bZ, long long bW, long long cZ,
    int swz)
{
    __shared__ u16 As[2][BM * BK];
    __shared__ u16 Bs[2][BN * BK];

    const int z = blockIdx.z;
    const int g = z / wmod, w = z - g * wmod;
    A  += g * aZ + w * aW;
    Bt += g * bZ + w * bW;
    C  += (long long)z * cZ;

    int bx = blockIdx.x, by = blockIdx.y;
    if (swz) {
        const int gx = gridDim.x;
        int id = by * gx + bx;
        int xcd = id & 7, j = id >> 3;
        bx = j % gx;
        by = (j / gx) * 8 + xcd;
    }

    const int tid = threadIdx.x;
    const int wave = tid >> 6, lane = tid & 63;
    const int wm = wave >> 1, wn = wave & 1;
    const int q = lane >> 4, r = lane & 15;

    const int ar = tid >> 2;
    const int ac = (((tid & 3) ^ ((tid >> 3) & 3)) << 3);
    const int ks = (r >> 1) & 3;

    const u16* Ag = A + (long long)(by * BM + ar) * lda + ac;
    const u16* Bg = Bt + (long long)(bx * BN + ar) * ldb + ac;
    const long long rstepA = 64LL * lda, rstepB = 64LL * ldb;

    f32x4 acc[4][4];
    const f32x4 zero = {0.f, 0.f, 0.f, 0.f};
#pragma unroll
    for (int i = 0; i < 4; ++i)
#pragma unroll
        for (int j = 0; j < 4; ++j) acc[i][j] = zero;

    const int nIter = K / BK;
    glds16(Ag, &As[0][tid * 8]);
    glds16(Ag + rstepA, &As[0][2048 + tid * 8]);
    glds16(Bg, &Bs[0][tid * 8]);
    glds16(Bg + rstepB, &Bs[0][2048 + tid * 8]);
    Ag += BK; Bg += BK;
    __syncthreads();
    for (int it = 0; it < nIter; ++it) {
        const int cur = it & 1, nxt = cur ^ 1;
        if (it + 1 < nIter) {
            glds16(Ag, &As[nxt][tid * 8]);
            glds16(Ag + rstepA, &As[nxt][2048 + tid * 8]);
            glds16(Bg, &Bs[nxt][tid * 8]);
            glds16(Bg + rstepB, &Bs[nxt][2048 + tid * 8]);
            Ag += BK; Bg += BK;
        }
        s16x8 af[4], bf[4];
#pragma unroll
        for (int mi = 0; mi < 4; ++mi)
            af[mi] = *(const s16x8*)(&As[cur][(wm * 64 + mi * 16 + r) * BK + ((q ^ ks) << 3)]);
#pragma unroll
        for (int ni = 0; ni < 4; ++ni)
            bf[ni] = *(const s16x8*)(&Bs[cur][(wn * 64 + ni * 16 + r) * BK + ((q ^ ks) << 3)]);
#pragma unroll
        for (int mi = 0; mi < 4; ++mi)
#pragma unroll
            for (int ni = 0; ni < 4; ++ni)
                acc[mi][ni] = __builtin_amdgcn_mfma_f32_16x16x32_bf16(
                    af[mi], bf[ni], acc[mi][ni], 0, 0, 0);
        __syncthreads();
    }

    const int col0 = bx * BN + wn * 64;
    const int row0 = by * BM + wm * 64;
#pragma unroll
    for (int ni = 0; ni < 4; ++ni) {
        const int colg = col0 + ni * 16 + r;
        float bv = 0.f;
        if constexpr (BIAS) bv = bf2f(bias[colg]);
#pragma unroll
        for (int mi = 0; mi < 4; ++mi) {
#pragma unroll
            for (int rr = 0; rr < 4; ++rr) {
                const int rowg = row0 + mi * 16 + q * 4 + rr;
                float v = acc[mi][ni][rr] + bv;
                if constexpr (RELU) v = fmaxf(v, 0.f);
                if constexpr (sizeof(OutT) == 2)
                    C[(long long)rowg * ldc + colg] = (OutT)f2bf(v);
                else
                    C[(long long)rowg * ldc + colg] = (OutT)v;
            }
        }
    }
}

// ---------------------------------------------------------------------------
// Flash attention. Block: 512 thr / 8 waves; Q-tile 64 rows; K-tile 128 keys.
// Role remap: batch = linear_id % G => each XCD (id%8 heuristic) serves one
// batch; K+Vt stay L2-resident and all blocks sweep kt in lockstep.
// Vt fragments prefetched into regs at kt-loop top (latency hidden by S1).
// ---------------------------------------------------------------------------
template <bool DIRECT>
__global__ __launch_bounds__(512, 2) void flash_attn(
    const u16* __restrict__ QKV,   // [G][3][S*D]
    const u16* __restrict__ Vt,    // [G][D*S]
    u16* __restrict__ O,           // [G][S*D] bf16 (DIRECT)
    float* __restrict__ Opart,     // [G*ns][S*D] fp32 (!DIRECT)
    float* __restrict__ rsPart,    // [G*ns][S] fp32 (!DIRECT)
    int nsplit)
{
    __shared__ u16 Qs[64 * 512];       // 64 KB, xor-swizzled 16B chunks
    __shared__ u16 Ks[2][128 * 128];   // 2 x 32 KB, xor-swizzled
    __shared__ u16 Ps[64 * 136];       // +8 pad per row (17 KB)
    __shared__ float rsL[8][64];

    const long long SD = 4096LL * 512;
    // linear id -> (g, sp, qb): g = id % G aligns batch with XCD round-robin
    const int G = gridDim.z;
    const int id = (blockIdx.z * gridDim.y + blockIdx.y) * gridDim.x + blockIdx.x;
    const int g = id % G;
    const int rest = id / G;
    const int sp = rest % nsplit;
    const int q0 = (rest / nsplit) * 64;

    const u16* Qg = QKV + ((long long)g * 3 + 0) * SD;
    const u16* Kg = QKV + ((long long)g * 3 + 1) * SD;
    const u16* Vg = Vt + (long long)g * SD;

    const int tid = threadIdx.x;
    const int wave = tid >> 6, lane = tid & 63;
    const int q = lane >> 4, r = lane & 15;
    const int mg = wave >> 2, ng = wave & 3;   // S1 roles (2 x 4)
    const int dg = wave;                       // PV role (d-range dg*64)

    // ---- stage Q tile (once), xor-swizzled chunks ----
#pragma unroll
    for (int i = 0; i < 8; ++i) {
        int L = i * 512 + tid;
        int row = L >> 6, p = L & 63;
        int l = p ^ (row & 15);
        glds16(Qg + (long long)(q0 + row) * 512 + l * 8, &Qs[L * 8]);
    }

    f32x4 oacc[4][4];
    const f32x4 zero = {0.f, 0.f, 0.f, 0.f};
#pragma unroll
    for (int i = 0; i < 4; ++i)
#pragma unroll
        for (int j = 0; j < 4; ++j) oacc[i][j] = zero;
    float rsum[2][4] = {{0.f, 0.f, 0.f, 0.f}, {0.f, 0.f, 0.f, 0.f}};

    const int span = 4096 / nsplit;
    const int kt0 = sp * span;
    const int ktN = span / 128;
    const float scale = 0.044194173824159216f;  // 1/sqrt(512)

    auto stageK = [&](int ktile, int kc, int buf) {
#pragma unroll
        for (int i = 0; i < 4; ++i) {
            int L = i * 512 + tid;
            int row = L >> 4, p = L & 15;
            int l = p ^ (row & 15);
            glds16(Kg + (long long)(kt0 + ktile * 128 + row) * 512 + kc * 128 + l * 8,
                   &Ks[buf][L * 8]);
        }
    };
    stageK(0, 0, 0);

    for (int kt = 0; kt < ktN; ++kt) {
        // ---- prefetch this kt's Vt fragments into regs (hidden by S1) ----
        const long long vbase = (long long)(dg * 64 + r) * 4096 + kt0 + kt * 128;
        s16x8 vf[4][4];
#pragma unroll
        for (int kc = 0; kc < 4; ++kc)
#pragma unroll
            for (int mi = 0; mi < 4; ++mi)
                vf[kc][mi] = *(const s16x8*)(Vg + vbase + (long long)mi * 16 * 4096
                                             + kc * 32 + q * 8);

        // ---- S1 = Q * Ktile^T ----
        f32x4 sacc[2][2];
#pragma unroll
        for (int i = 0; i < 2; ++i)
#pragma unroll
            for (int j = 0; j < 2; ++j) sacc[i][j] = zero;

        for (int kc = 0; kc < 4; ++kc) {
            if (kc < 3) stageK(kt, kc + 1, (kc + 1) & 1);
            __syncthreads();
            const u16* Kb = Ks[kc & 1];
#pragma unroll
            for (int sc = 0; sc < 4; ++sc) {
                s16x8 af[2], bf[2];
#pragma unroll
                for (int mi = 0; mi < 2; ++mi) {
                    int row = (mg * 2 + mi) * 16 + r;
                    int l = kc * 16 + sc * 4 + q;
                    af[mi] = *(const s16x8*)&Qs[row * 512 + ((l ^ r) << 3)];
                }
#pragma unroll
                for (int ni = 0; ni < 2; ++ni) {
                    int row = (ng * 2 + ni) * 16 + r;
                    int l = sc * 4 + q;
                    bf[ni] = *(const s16x8*)&Kb[row * 128 + ((l ^ r) << 3)];
                }
#pragma unroll
                for (int mi = 0; mi < 2; ++mi)
#pragma unroll
                    for (int ni = 0; ni < 2; ++ni)
                        sacc[mi][ni] = __builtin_amdgcn_mfma_f32_16x16x32_bf16(
                            af[mi], bf[ni], sacc[mi][ni], 0, 0, 0);
            }
        }
        // ---- P = exp, write Ps, accumulate rowsums ----
#pragma unroll
        for (int mi = 0; mi < 2; ++mi) {
#pragma unroll
            for (int ni = 0; ni < 2; ++ni) {
                int col = (ng * 2 + ni) * 16 + r;
#pragma unroll
                for (int rr = 0; rr < 4; ++rr) {
                    int row = (mg * 2 + mi) * 16 + q * 4 + rr;
                    float v = __expf(fminf(sacc[mi][ni][rr] * scale, 30.f));
                    Ps[row * 136 + col] = f2bf(v);
                    rsum[mi][rr] += v;
                }
            }
        }
        if (kt + 1 < ktN) stageK(kt + 1, 0, 0);  // Ks[0] free (last read kc=2)
        __syncthreads();                          // Ps visible to all waves
        // ---- PV: O^T += Vt * P^T (Vt from vf regs, P from LDS) ----
#pragma unroll
        for (int kc = 0; kc < 4; ++kc) {
            s16x8 bf[4];
#pragma unroll
            for (int ni = 0; ni < 4; ++ni)
                bf[ni] = *(const s16x8*)&Ps[(ni * 16 + r) * 136 + kc * 32 + q * 8];
#pragma unroll
            for (int mi = 0; mi < 4; ++mi)
#pragma unroll
                for (int ni = 0; ni < 4; ++ni)
                    oacc[mi][ni] = __builtin_amdgcn_mfma_f32_16x16x32_bf16(
                        vf[kc][mi], bf[ni], oacc[mi][ni], 0, 0, 0);
        }
    }

    // ---- finalize rowsums ----
#pragma unroll
    for (int mi = 0; mi < 2; ++mi)
#pragma unroll
        for (int rr = 0; rr < 4; ++rr) {
            float s = rsum[mi][rr];
#pragma unroll
            for (int m = 1; m < 16; m <<= 1) s += __shfl_xor(s, m);
            rsum[mi][rr] = s;
        }
    if (r == 0) {
#pragma unroll
        for (int mi = 0; mi < 2; ++mi)
#pragma unroll
            for (int rr = 0; rr < 4; ++rr)
                rsL[wave][(mg * 2 + mi) * 16 + q * 4 + rr] = rsum[mi][rr];
    }
    __syncthreads();

    if constexpr (DIRECT) {
        u16* Og = O + (long long)g * SD;
#pragma unroll
        for (int ni = 0; ni < 4; ++ni) {
            int qrow = ni * 16 + r;
            int wb = (qrow >> 5) * 4;
            float rs = rsL[wb][qrow] + rsL[wb + 1][qrow]
                     + rsL[wb + 2][qrow] + rsL[wb + 3][qrow];
            float inv = 1.f / rs;
#pragma unroll
            for (int mi = 0; mi < 4; ++mi) {
                int d = (dg * 4 + mi) * 16 + q * 4;
                ushort4 o4;
                o4.x = f2bf(oacc[mi][ni][0] * inv);
                o4.y = f2bf(oacc[mi][ni][1] * inv);
                o4.z = f2bf(oacc[mi][ni][2] * inv);
                o4.w = f2bf(oacc[mi][ni][3] * inv);
                *(ushort4*)&Og[(long long)(q0 + qrow) * 512 + d] = o4;
            }
        }
    } else {
        const int pb = g * nsplit + sp;
        float* Op = Opart + (long long)pb * SD;
#pragma unroll
        for (int ni = 0; ni < 4; ++ni) {
            int qrow = ni * 16 + r;
#pragma unroll
            for (int mi = 0; mi < 4; ++mi) {
                int d = (dg * 4 + mi) * 16 + q * 4;
                float4 o4;
                o4.x = oacc[mi][ni][0]; o4.y = oacc[mi][ni][1];
                o4.z = oacc[mi][ni][2]; o4.w = oacc[mi][ni][3];
                *(float4*)&Op[(long long)(q0 + qrow) * 512 + d] = o4;
            }
        }
        if (tid < 64) {
            int wb = (tid >> 5) * 4;
            rsPart[(long long)pb * 4096 + q0 + tid] =
                rsL[wb][tid] + rsL[wb + 1][tid] + rsL[wb + 2][tid] + rsL[wb + 3][tid];
        }
    }
}

// reduce partial O / rowsums -> bf16 O.  grid (1024, G)
__global__ __launch_bounds__(256) void reduce_flash(
    const float* __restrict__ Opart, const float* __restrict__ rsPart,
    u16* __restrict__ O, int ns)
{
    const long long SD = 4096LL * 512;
    const int g = blockIdx.y;
    u16* Og = O + (long long)g * SD;
    const int base = blockIdx.x * 2048;
#pragma unroll
    for (int it = 0; it < 8; ++it) {
        int i = base + it * 256 + threadIdx.x;
        int row = i >> 9;
        float s = 0.f, rs = 0.f;
        for (int sp = 0; sp < ns; ++sp) {
            s += Opart[(long long)(g * ns + sp) * SD + i];
            rs += rsPart[(long long)(g * ns + sp) * 4096 + row];
        }
        Og[i] = f2bf(s / rs);
    }
}

// ---------------------------------------------------------------------------
__global__ __launch_bounds__(256) void transpose_any(
    const void* __restrict__ in, u16* __restrict__ out, int R, int C,
    long long sIn, long long sOut, const int* __restrict__ flag)
{
    __shared__ u16 tile[32][33];
    const int f32 = *flag;
    const long long ib = (long long)blockIdx.z * sIn;
    u16* ob = out + (long long)blockIdx.z * sOut;
    const int c0 = blockIdx.x * 32, r0 = blockIdx.y * 32;
    const int tx = threadIdx.x, ty = threadIdx.y;
#pragma unroll
    for (int i = 0; i < 4; ++i) {
        int rr = ty + i * 8;
        tile[rr][tx] = loadbf(in, ib + (long long)(r0 + rr) * C + c0 + tx, f32);
    }
    __syncthreads();
#pragma unroll
    for (int i = 0; i < 4; ++i) {
        int cc = ty + i * 8;
        ob[(long long)(c0 + cc) * R + r0 + tx] = tile[tx][cc];
    }
}

__global__ __launch_bounds__(256) void transpose_b16(
    const u16* __restrict__ in, u16* __restrict__ out, int R, int C,
    long long sIn, long long sOut)
{
    __shared__ u16 tile[32][33];
    in += (long long)blockIdx.z * sIn;
    out += (long long)blockIdx.z * sOut;
    const int c0 = blockIdx.x * 32, r0 = blockIdx.y * 32;
    const int tx = threadIdx.x, ty = threadIdx.y;
#pragma unroll
    for (int i = 0; i < 4; ++i) {
        int rr = ty + i * 8;
        tile[rr][tx] = in[(long long)(r0 + rr) * C + c0 + tx];
    }
    __syncthreads();
#pragma unroll
    for (int i = 0; i < 4; ++i) {
        int cc = ty + i * 8;
        out[(long long)(c0 + cc) * R + r0 + tx] = tile[tx][cc];
    }
}

__global__ __launch_bounds__(256) void convert_bias(
    const void* __restrict__ b1, const void* __restrict__ b2,
    u16* __restrict__ ob, const int* __restrict__ f1, const int* __restrict__ f2)
{
    int i = blockIdx.x * 256 + threadIdx.x;
    if (i < 2048) ob[i] = loadbf(b1, i, *f1);
    else if (i < 2560) ob[i] = loadbf(b2, i - 2048, *f2);
}

// ---------------------------------------------------------------------------
// Norm helpers
// ---------------------------------------------------------------------------
__global__ __launch_bounds__(256) void stats_add_partial(
    const u16* __restrict__ A, const u16* __restrict__ Bv,
    float2* __restrict__ partial)
{
    const int b = blockIdx.y;
    const long long yb = (long long)b * (4096LL * 512);
    const int base = blockIdx.x * 2048;
    float s = 0.f, ss = 0.f;
#pragma unroll
    for (int it = 0; it < 8; ++it) {
        int i = base + it * 256 + threadIdx.x;
        float z = bf2f(A[yb + i]) + bf2f(Bv[yb + i]);
        s += z; ss += z * z;
    }
#pragma unroll
    for (int off = 32; off > 0; off >>= 1) {
        s += __shfl_down(s, off); ss += __shfl_down(ss, off);
    }
    __shared__ float red[8];
    int lane = threadIdx.x & 63, wave = threadIdx.x >> 6;
    if (lane == 0) { red[wave * 2] = s; red[wave * 2 + 1] = ss; }
    __syncthreads();
    if (threadIdx.x == 0) {
        for (int w = 1; w < 4; ++w) { s += red[w * 2]; ss += red[w * 2 + 1]; }
        partial[b * 1024 + blockIdx.x] = make_float2(s, ss);
    }
}

__global__ __launch_bounds__(256) void stats_finish(
    const float2* __restrict__ partial, float2* __restrict__ stats, float N)
{
    const int b = blockIdx.x;
    float s = 0.f, ss = 0.f;
    for (int i = threadIdx.x; i < 1024; i += 256) {
        float2 p = partial[b * 1024 + i];
        s += p.x; ss += p.y;
    }
#pragma unroll
    for (int off = 32; off > 0; off >>= 1) {
        s += __shfl_down(s, off); ss += __shfl_down(ss, off);
    }
    __shared__ float red[8];
    int lane = threadIdx.x & 63, wave = threadIdx.x >> 6;
    if (lane == 0) { red[wave * 2] = s; red[wave * 2 + 1] = ss; }
    __syncthreads();
    if (threadIdx.x == 0) {
        for (int w = 1; w < 4; ++w) { s += red[w * 2]; ss += red[w * 2 + 1]; }
        float mean = s / N;
        float l2 = sqrtf(fmaxf(ss - s * s / N, 0.f));
        stats[b] = make_float2(mean, 1.f / (l2 + 1e-7f));
    }
}

__global__ __launch_bounds__(256) void post_kernel(
    const u16* __restrict__ A, const u16* __restrict__ Bv,
    const float2* __restrict__ stats, u16* __restrict__ post)
{
    const int b = blockIdx.y;
    const float2 st = stats[b];
    const long long yb = (long long)b * (4096LL * 512);
    const int base = blockIdx.x * 2048;
#pragma unroll
    for (int it = 0; it < 8; ++it) {
        int i = base + it * 256 + threadIdx.x;
        float z = bf2f(A[yb + i]) + bf2f(Bv[yb + i]);
        post[yb + i] = f2bf((z - st.x) * st.y);
    }
}

__global__ __launch_bounds__(256) void final_kernel(
    const u16* __restrict__ P, const u16* __restrict__ G,
    const float2* __restrict__ stats, float* __restrict__ out)
{
    __shared__ float tile[32][33];
    const int b = blockIdx.z;
    const float2 st = stats[b];
    const long long bb = (long long)b * (4096LL * 512);
    const int s0 = blockIdx.x * 32, d0 = blockIdx.y * 32;
    const int tx = threadIdx.x, ty = threadIdx.y;
#pragma unroll
    for (int i = 0; i < 4; ++i) {
        int sl = ty + i * 8;
        long long idx = bb + (long long)(s0 + sl) * 512 + d0 + tx;
        tile[sl][tx] = bf2f(P[idx]) + bf2f(G[idx]);
    }
    __syncthreads();
#pragma unroll
    for (int i = 0; i < 4; ++i) {
        int dl = ty + i * 8;
        out[bb + (long long)(d0 + dl) * 4096 + s0 + tx] =
            (tile[tx][dl] - st.x) * st.y;
    }
}

// ---------------------------------------------------------------------------
extern "C" void kernel_launch(void* const* d_in, const int* in_sizes, int n_in,
                              void* d_out, int out_size, void* d_ws, size_t ws_size,
                              hipStream_t stream)
{
    (void)out_size;
    const void* x  = d_in[0];
    const void* Wq = d_in[1];
    const void* Wk = d_in[2];
    const void* Wv = d_in[3];
    const void* Wo = d_in[4];
    const void* W1 = d_in[5];
    const void* b1 = d_in[6];
    const void* W2 = d_in[7];
    const void* b2 = d_in[8];

    const int Bb = 8, D = 512, S = 4096, F = 2048;
    const long long SD = (long long)S * D;
    const long long DD = (long long)D * D;

    char* ws = (char*)d_ws;
    size_t off = 0;
    auto take = [&](size_t bytes) -> char* {
        char* p = ws + off;
        off += (bytes + 255) & ~(size_t)255;
        return p;
    };
    u16* xt   = (u16*)take((size_t)Bb * SD * 2);   // [B,S,D] 33.5 MB
    u16* WqT  = (u16*)take((size_t)DD * 2);
    u16* WkT  = (u16*)take((size_t)DD * 2);
    u16* WvT  = (u16*)take((size_t)DD * 2);
    u16* WoT  = (u16*)take((size_t)DD * 2);
    u16* W1T  = (u16*)take((size_t)D * F * 2);
    u16* W2T  = (u16*)take((size_t)D * F * 2);
    u16* bb   = (u16*)take(2560 * 2);
    u16* post = (u16*)take((size_t)Bb * SD * 2);   // 33.5 MB; Opart/Y overlay
    float2* npart  = (float2*)take(8 * 1024 * sizeof(float2));
    float2* stats1v = (float2*)take(256);
    float2* stats2v = (float2*)take(256);
    int* flags = (int*)take(16 * sizeof(int));
    float* rsPart = (float*)take(4 * 4096 * sizeof(float));

    size_t remaining = ws_size > off ? ws_size - off : 0;
    const size_t perG = (size_t)4 * SD * 2 + 4096;
    int G = (remaining >= 8 * perG) ? 8 : (remaining >= 4 * perG) ? 4 : 2;
    int ns = (G >= 4) ? 1 : 2;

    u16* attnBuf = (u16*)take((size_t)4 * G * SD * 2);  // [G][3][S,D] + [G][D,S]
    u16* QKVb = attnBuf;
    u16* Vtb  = attnBuf + (size_t)3 * G * SD;
    float* Opart = (float*)post;
    u16* Oall = (u16*)d_out;
    u16* Y    = post;
    u16* Hbuf = (u16*)d_out;
    u16* Gbuf = attnBuf;

    DetectArgs da;
    for (int i = 0; i < 9; ++i) {
        da.p[i] = (const u16*)d_in[i];
        da.n[i] = (i < n_in && in_sizes[i] < 8192) ? in_sizes[i] : 8192;
    }
    detect9<<<dim3(9), 256, 0, stream>>>(da, flags);

    dim3 tb(32, 8, 1);
    transpose_any<<<dim3(S / 32, D / 32, Bb), tb, 0, stream>>>(x, xt, D, S, SD, SD, flags + 0);
    transpose_any<<<dim3(16, 16, 1), tb, 0, stream>>>(Wq, WqT, D, D, 0, 0, flags + 1);
    transpose_any<<<dim3(16, 16, 1), tb, 0, stream>>>(Wk, WkT, D, D, 0, 0, flags + 2);
    transpose_any<<<dim3(16, 16, 1), tb, 0, stream>>>(Wv, WvT, D, D, 0, 0, flags + 3);
    transpose_any<<<dim3(16, 16, 1), tb, 0, stream>>>(Wo, WoT, D, D, 0, 0, flags + 4);
    transpose_any<<<dim3(F / 32, D / 32, 1), tb, 0, stream>>>(W1, W1T, D, F, 0, 0, flags + 5);
    transpose_any<<<dim3(D / 32, F / 32, 1), tb, 0, stream>>>(W2, W2T, F, D, 0, 0, flags + 7);
    convert_bias<<<10, 256, 0, stream>>>(b1, b2, bb, flags + 6, flags + 8);

    // ---- attention ----
    for (int b0 = 0; b0 < Bb; b0 += G) {
        gemm_bt<u16, false, false><<<dim3(D / 128, S / 128, 3 * G), 256, 0, stream>>>(
            xt + (long long)b0 * SD, WqT, QKVb, nullptr, S, D, D, D, D, D,
            3, SD, 0, 0, DD, SD, 1);
        transpose_b16<<<dim3(D / 32, S / 32, G), tb, 0, stream>>>(
            QKVb + 2 * SD, Vtb, S, D, 3 * SD, SD);
        if (ns == 1) {
            flash_attn<true><<<dim3(64, 1, G), 512, 0, stream>>>(
                QKVb, Vtb, Oall + (long long)b0 * SD, nullptr, nullptr, 1);
        } else {
            flash_attn<false><<<dim3(64, ns, G), 512, 0, stream>>>(
                QKVb, Vtb, nullptr, Opart, rsPart, ns);
            reduce_flash<<<dim3(1024, G), 256, 0, stream>>>(
                Opart, rsPart, Oall + (long long)b0 * SD, ns);
        }
    }

    // Y = O @ Wo
    gemm_bt<u16, false, false><<<dim3(D / 128, (Bb * S) / 128, 1), 256, 0, stream>>>(
        Oall, WoT, Y, nullptr, Bb * S, D, D, D, D, D, 1, 0, 0, 0, 0, 0, 1);

    // post = norm(xt + Y)
    stats_add_partial<<<dim3(1024, Bb), 256, 0, stream>>>(xt, Y, npart);
    stats_finish<<<dim3(Bb), 256, 0, stream>>>(npart, stats1v, (float)SD);
    post_kernel<<<dim3(1024, Bb), 256, 0, stream>>>(xt, Y, stats1v, post);

    // FFN halves: H in d_out, G in attnBuf
    for (int h = 0; h < 2; ++h) {
        gemm_bt<u16, true, true><<<dim3(F / 128, (4 * S) / 128, 1), 256, 0, stream>>>(
            post + (long long)h * 4 * SD, W1T, Hbuf, bb, 4 * S, F, D, D, D, F,
            1, 0, 0, 0, 0, 0, 1);
        gemm_bt<u16, true, false><<<dim3(D / 128, (4 * S) / 128, 1), 256, 0, stream>>>(
            Hbuf, W2T, Gbuf + (long long)h * 4 * SD, bb + 2048, 4 * S, D, F, F, F, D,
            1, 0, 0, 0, 0, 0, 1);
    }

    // out = norm(post + G), transposed to [B,D,S], fp32
    stats_add_partial<<<dim3(1024, Bb), 256, 0, stream>>>(post, Gbuf, npart);
    stats_finish<<<dim3(Bb), 256, 0, stream>>>(npart, stats2v, (float)SD);
    final_kernel<<<dim3(S / 32, D / 32, Bb), tb, 0, stream>>>(
        post, Gbuf, stats2v, (float*)d_out);
}